// Round 7
// baseline (48.877 us; speedup 1.0000x reference)
//
#include <hip/hip_runtime.h>
#include <hip/hip_bf16.h>
#include <stdint.h>

#define N_ROWS 8192
#define M_ROWS 16384
#define CDIM 128
#define NT 32      // 64-row B tiles per block (2048 rows per msplit)
#define BROWS 64

typedef unsigned short u16;
typedef __attribute__((ext_vector_type(2))) unsigned short u16x2;
typedef __attribute__((ext_vector_type(8))) short bf16x8;
typedef __attribute__((ext_vector_type(4))) float f32x4;

static __device__ __forceinline__ u16 f2bf(float x) {
  union { float f; uint32_t u; } v; v.f = x;
  uint32_t u = v.u;
  uint32_t r = u + 0x7FFFu + ((u >> 16) & 1u);  // RTNE
  return (u16)(r >> 16);
}
static __device__ __forceinline__ float bf2f(u16 b) {
  union { uint32_t u; float f; } v; v.u = ((uint32_t)b) << 16;
  return v.f;
}

// One wave per row: fp32 -> bf16 copies, row sum-of-squares of the
// bf16-rounded values (fp32 accum). For memory rows, stores mh = -0.5*||m||^2
// (folded into the MFMA C-init by the gemm). Inits the min-d2 buffer.
__global__ __launch_bounds__(256) void prep_kernel(
    const float* __restrict__ f, const float* __restrict__ m,
    u16* __restrict__ fb, u16* __restrict__ mb,
    float* __restrict__ f2, float* __restrict__ mh, int* __restrict__ mind2)
{
  const int row = blockIdx.x * 4 + (threadIdx.x >> 6);
  const int lane = threadIdx.x & 63;
  const bool isF = row < N_ROWS;
  const float* src = isF ? (f + (size_t)row * CDIM)
                         : (m + (size_t)(row - N_ROWS) * CDIM);
  float2 v = *(const float2*)(src + lane * 2);
  u16 b0 = f2bf(v.x), b1 = f2bf(v.y);
  float x0 = bf2f(b0), x1 = bf2f(b1);
  float s = x0 * x0 + x1 * x1;
#pragma unroll
  for (int mask = 1; mask < 64; mask <<= 1)
    s += __shfl_xor(s, mask, 64);
  u16x2 bb = {b0, b1};
  if (isF) {
    *(u16x2*)(fb + (size_t)row * CDIM + lane * 2) = bb;
    if (lane == 0) { f2[row] = s; mind2[row] = 0x7F7FFFFF; }  // +FLT_MAX bits
  } else {
    const int r = row - N_ROWS;
    *(u16x2*)(mb + (size_t)r * CDIM + lane * 2) = bb;
    if (lane == 0) mh[r] = -0.5f * s;
  }
}

// 128(A-rows) x 64(B-rows) per tile, 4 waves (2x2: 64 A-rows x 32 B-rows
// each). A in registers (full K=128). B double-buffered 16 KB tiles, staged
// via source-preswizzled global_load_lds (linear LDS dest; reads apply
// byte ^= ((row&7)<<4)). Main loop: ONE s_barrier per tile + counted
// vmcnt(4) — staging loads stay in flight across the barrier (T4); no
// vmcnt(0) drain anywhere in the loop. mh=-m2/2 lives in LDS and seeds the
// MFMA accumulator, so min(m2-2*cross) = -2*max(acc): epilogue is 32 fmax.
// grid = (8 msplit, 64 ntile): linear id % 8 == msplit == XCD -> each XCD's
// L2 holds one 512 KB B-slice.
__global__ __launch_bounds__(256, 2) void gemm_min_kernel(
    const u16* __restrict__ fb, const u16* __restrict__ mb,
    const float* __restrict__ f2, const float* __restrict__ mh,
    int* __restrict__ mind2)
{
  __shared__ __align__(16) u16 bts[2][BROWS * CDIM];  // 2 x 16 KB B tiles
  __shared__ __align__(16) float mhl[2048];           // -m2/2 slice (8 KB)
  const int tid = threadIdx.x;
  const int msplit = blockIdx.x;
  const int nbase = blockIdx.y * 128;

  const int lane = tid & 63;
  const int w = tid >> 6;
  const int wr = w >> 1, wc = w & 1;
  const int l15 = lane & 15, l4 = lane >> 4;
  const int sw = (l15 & 7) << 4;  // read-side XOR (bytes)

  // Per-thread staging offsets (4 x 16B chunks per 16 KB tile).
  int srcOffs[4], dstOffs[4];
#pragma unroll
  for (int c = 0; c < 4; ++c) {
    const int t16 = c * 256 + tid;
    srcOffs[c] = (t16 ^ ((t16 >> 4) & 7)) * 8;  // u16 units
    dstOffs[c] = t16 * 8;
  }

  // ---- Prologue: stage A (32 KB, spans both B buffers) + mh slice ----
  {
    const u16* srcA = fb + (size_t)nbase * CDIM;
    u16* base = &bts[0][0];
#pragma unroll
    for (int c = 0; c < 8; ++c) {
      const int t16 = c * 256 + tid;
      const int so = (t16 ^ ((t16 >> 4) & 7)) * 8;
      __builtin_amdgcn_global_load_lds(
          (const __attribute__((address_space(1))) uint32_t*)(srcA + so),
          (__attribute__((address_space(3))) uint32_t*)(base + t16 * 8), 16, 0, 0);
    }
    const float* srcM = mh + msplit * 2048;
#pragma unroll
    for (int c = 0; c < 2; ++c) {
      const int c16 = c * 256 + tid;
      __builtin_amdgcn_global_load_lds(
          (const __attribute__((address_space(1))) uint32_t*)(srcM + c16 * 4),
          (__attribute__((address_space(3))) uint32_t*)(&mhl[c16 * 4]), 16, 0, 0);
    }
  }
  asm volatile("s_waitcnt vmcnt(0)" ::: "memory");
  __builtin_amdgcn_s_barrier();

  // A fragments -> registers (64 VGPRs), swizzled read.
  bf16x8 af[4][4];  // [mi][ks]
  {
    const u16* base = &bts[0][0];
#pragma unroll
    for (int mi = 0; mi < 4; ++mi)
#pragma unroll
      for (int ks = 0; ks < 4; ++ks) {
        const int row = wr * 64 + mi * 16 + l15;
        const int cb = (ks * 64 + l4 * 16) ^ sw;
        af[mi][ks] = *(const bf16x8*)&base[row * CDIM + (cb >> 1)];
      }
  }
  __syncthreads();  // all waves done reading A; buffers free

  // Kick the pipeline: stage tile 0 -> buf 0.
  {
    const u16* srcB = mb + (size_t)(msplit * 2048) * CDIM;
    u16* dstB = &bts[0][0];
#pragma unroll
    for (int c = 0; c < 4; ++c)
      __builtin_amdgcn_global_load_lds(
          (const __attribute__((address_space(1))) uint32_t*)(srcB + srcOffs[c]),
          (__attribute__((address_space(3))) uint32_t*)(dstB + dstOffs[c]), 16, 0, 0);
  }

  float tmax[4][4];
#pragma unroll
  for (int mi = 0; mi < 4; ++mi)
#pragma unroll
    for (int j = 0; j < 4; ++j) tmax[mi][j] = -3.0e38f;

  for (int t = 0; t < NT; ++t) {
    // All waves done reading buf[(t-1)&1] -> safe to overwrite with t+1.
    __builtin_amdgcn_s_barrier();
    asm volatile("" ::: "memory");  // pin staging after the barrier
    {
      const int tn = (t + 1) & (NT - 1);  // t=NT-1 wraps to a harmless dummy
      const u16* srcB = mb + (size_t)(msplit * 2048 + tn * BROWS) * CDIM;
      u16* dstB = &bts[(t + 1) & 1][0];
#pragma unroll
      for (int c = 0; c < 4; ++c)
        __builtin_amdgcn_global_load_lds(
            (const __attribute__((address_space(1))) uint32_t*)(srcB + srcOffs[c]),
            (__attribute__((address_space(3))) uint32_t*)(dstB + dstOffs[c]), 16, 0, 0);
    }
    // Wait for THIS tile's 4 loads (issued one full iteration ago);
    // next tile's 4 remain in flight across the barrier.
    asm volatile("s_waitcnt vmcnt(4)" ::: "memory");

    const u16* bt = &bts[t & 1][0];
    const int brow0 = wc * 32 + l15;
    const float mh0 = mhl[t * BROWS + brow0];
    const float mh1 = mhl[t * BROWS + brow0 + 16];

    f32x4 acc[4][2];
#pragma unroll
    for (int mi = 0; mi < 4; ++mi) {
      acc[mi][0] = (f32x4){mh0, mh0, mh0, mh0};
      acc[mi][1] = (f32x4){mh1, mh1, mh1, mh1};
    }

    __builtin_amdgcn_s_setprio(1);
#pragma unroll
    for (int ks = 0; ks < 4; ++ks) {
      const int cb = (ks * 64 + l4 * 16) ^ sw;
      const bf16x8 bg0 = *(const bf16x8*)&bt[brow0 * CDIM + (cb >> 1)];
      const bf16x8 bg1 = *(const bf16x8*)&bt[(brow0 + 16) * CDIM + (cb >> 1)];
#pragma unroll
      for (int mi = 0; mi < 4; ++mi) {
        acc[mi][0] = __builtin_amdgcn_mfma_f32_16x16x32_bf16(
            af[mi][ks], bg0, acc[mi][0], 0, 0, 0);
        acc[mi][1] = __builtin_amdgcn_mfma_f32_16x16x32_bf16(
            af[mi][ks], bg1, acc[mi][1], 0, 0, 0);
      }
    }
    __builtin_amdgcn_s_setprio(0);

    // acc = cross - m2/2; running max -> min distance later.
#pragma unroll
    for (int mi = 0; mi < 4; ++mi)
#pragma unroll
      for (int j = 0; j < 4; ++j)
        tmax[mi][j] = fmaxf(tmax[mi][j], fmaxf(acc[mi][0][j], acc[mi][1][j]));
  }

  // Max across the 16 lanes (l15) holding a row's columns.
#pragma unroll
  for (int mi = 0; mi < 4; ++mi)
#pragma unroll
    for (int j = 0; j < 4; ++j) {
      float tv = tmax[mi][j];
      tv = fmaxf(tv, __shfl_xor(tv, 1, 64));
      tv = fmaxf(tv, __shfl_xor(tv, 2, 64));
      tv = fmaxf(tv, __shfl_xor(tv, 4, 64));
      tv = fmaxf(tv, __shfl_xor(tv, 8, 64));
      tmax[mi][j] = tv;
    }
  if (l15 == 0) {
#pragma unroll
    for (int mi = 0; mi < 4; ++mi)
#pragma unroll
      for (int j = 0; j < 4; ++j) {
        const int row = nbase + wr * 64 + mi * 16 + l4 * 4 + j;
        // d2 = f2 + min(m2 - 2*cross) = f2 - 2*max(acc); >= 0 -> int-ordered
        const float d2 = fmaxf(fmaf(-2.0f, tmax[mi][j], f2[row]), 0.0f);
        atomicMin(&mind2[row], __float_as_int(d2));
      }
  }
}

__global__ __launch_bounds__(256) void finalize_kernel(
    const int* __restrict__ mind2, float* __restrict__ out)
{
  const int i = blockIdx.x * 256 + threadIdx.x;
  out[i] = sqrtf(fmaxf(__int_as_float(mind2[i]), 0.0f));
}

extern "C" void kernel_launch(void* const* d_in, const int* in_sizes, int n_in,
                              void* d_out, int out_size, void* d_ws, size_t ws_size,
                              hipStream_t stream) {
  const float* f = (const float*)d_in[0];  // features  [8192,1,1,128] fp32
  const float* m = (const float*)d_in[1];  // patch_mem [1,16384,1,128] fp32

  char* ws = (char*)d_ws;
  u16*  fb    = (u16*)(ws);                                   // 2 MB
  u16*  mb    = (u16*)(ws + (2u << 20));                      // 4 MB
  float* f2   = (float*)(ws + (2u << 20) + (4u << 20));       // 32 KB
  float* mh   = (float*)(ws + (2u << 20) + (4u << 20) + (32u << 10));  // 64 KB
  int*  mind2 = (int*)(ws + (2u << 20) + (4u << 20) + (96u << 10));    // 32 KB

  hipLaunchKernelGGL(prep_kernel, dim3((N_ROWS + M_ROWS) / 4), dim3(256), 0, stream,
                     f, m, fb, mb, f2, mh, mind2);
  hipLaunchKernelGGL(gemm_min_kernel, dim3(8, N_ROWS / 128), dim3(256), 0, stream,
                     fb, mb, f2, mh, mind2);
  hipLaunchKernelGGL(finalize_kernel, dim3(N_ROWS / 256), dim3(256), 0, stream,
                     mind2, (float*)d_out);
}

// Round 8
// 46.202 us; speedup vs baseline: 1.0579x; 1.0579x over previous
//
#include <hip/hip_runtime.h>
#include <hip/hip_bf16.h>
#include <stdint.h>

#define N_ROWS 8192
#define M_ROWS 16384
#define CDIM 128
#define NTILE 16    // B tiles per block: 16 x 128 rows = 2048 rows per msplit
#define BTROWS 128

typedef unsigned short u16;
typedef __attribute__((ext_vector_type(2))) unsigned short u16x2;
typedef __attribute__((ext_vector_type(8))) short bf16x8;
typedef __attribute__((ext_vector_type(4))) float f32x4;

static __device__ __forceinline__ u16 f2bf(float x) {
  union { float f; uint32_t u; } v; v.f = x;
  uint32_t u = v.u;
  uint32_t r = u + 0x7FFFu + ((u >> 16) & 1u);  // RTNE
  return (u16)(r >> 16);
}
static __device__ __forceinline__ float bf2f(u16 b) {
  union { uint32_t u; float f; } v; v.u = ((uint32_t)b) << 16;
  return v.f;
}

#define GLOAD_LDS(gsrc, ldst)                                                  \
  __builtin_amdgcn_global_load_lds(                                            \
      (const __attribute__((address_space(1))) uint32_t*)(gsrc),               \
      (__attribute__((address_space(3))) uint32_t*)(ldst), 16, 0, 0)

// One wave per row: fp32 -> bf16 copies, row sum-of-squares of the
// bf16-rounded values (fp32 accum). Memory rows store mh = -0.5*||m||^2
// (seeds the MFMA accumulator in the gemm). Inits the min-d2 buffer.
__global__ __launch_bounds__(256) void prep_kernel(
    const float* __restrict__ f, const float* __restrict__ m,
    u16* __restrict__ fb, u16* __restrict__ mb,
    float* __restrict__ f2, float* __restrict__ mh, int* __restrict__ mind2)
{
  const int row = blockIdx.x * 4 + (threadIdx.x >> 6);
  const int lane = threadIdx.x & 63;
  const bool isF = row < N_ROWS;
  const float* src = isF ? (f + (size_t)row * CDIM)
                         : (m + (size_t)(row - N_ROWS) * CDIM);
  float2 v = *(const float2*)(src + lane * 2);
  u16 b0 = f2bf(v.x), b1 = f2bf(v.y);
  float x0 = bf2f(b0), x1 = bf2f(b1);
  float s = x0 * x0 + x1 * x1;
#pragma unroll
  for (int mask = 1; mask < 64; mask <<= 1)
    s += __shfl_xor(s, mask, 64);
  u16x2 bb = {b0, b1};
  if (isF) {
    *(u16x2*)(fb + (size_t)row * CDIM + lane * 2) = bb;
    if (lane == 0) { f2[row] = s; mind2[row] = 0x7F7FFFFF; }  // +FLT_MAX bits
  } else {
    const int r = row - N_ROWS;
    *(u16x2*)(mb + (size_t)r * CDIM + lane * 2) = bb;
    if (lane == 0) mh[r] = -0.5f * s;
  }
}

// 8-wave phase-template port. Block = 512 thr (8 waves, 4 wm x 2 wn), block
// tile 256 A-rows x 128 B-rows/tile, wave = 64x64. A in registers (full
// K=128). B TRIPLE-buffered 32 KB tiles with 2-tile-lookahead staging:
// per tile, 4 phases of {fold/seed | 4 bg ds_read | 1 stage issue ->
// s_barrier -> sched_barrier -> setprio(1) -> 16 MFMA -> setprio(0)};
// vmcnt(4) once per tile (phase 3, before the barrier) waits only loads
// issued a full tile earlier -- the staging queue NEVER drains to 0, and
// vmcnt->barrier->read makes cross-wave LDS visibility provably safe.
// acc is seeded with mh=-m2/2, so min d2 = f2 - 2*max(acc).
// grid = (8 msplit, 32 ntile): linear%8 = msplit = XCD -> per-XCD B-slice.
__global__ __launch_bounds__(512, 2) void gemm_min_kernel(
    const u16* __restrict__ fb, const u16* __restrict__ mb,
    const float* __restrict__ f2, const float* __restrict__ mh,
    int* __restrict__ mind2)
{
  __shared__ __align__(16) u16 bts[3 * BTROWS * CDIM];  // 96 KB: 3 B buffers
  __shared__ __align__(16) float mhl[2048];             // 8 KB: -m2/2 slice
  const int tid = threadIdx.x;
  const int msplit = blockIdx.x;
  const int nbase = blockIdx.y * 256;

  const int lane = tid & 63;
  const int w = tid >> 6;    // 0..7
  const int wm = w >> 1;     // 0..3 : 64-row A group
  const int wn = w & 1;      // 0..1 : 64-row B group
  const int l15 = lane & 15, l4 = lane >> 4;
  const int sw = (l15 & 7) << 4;  // read-side XOR (bytes)

  // ---- Prologue: stage A (64 KB, buffers 0-1) + mh slice ----
  {
    const u16* srcA = fb + (size_t)nbase * CDIM;
#pragma unroll
    for (int c = 0; c < 8; ++c) {
      const int t16 = c * 512 + tid;
      const int so = (t16 ^ ((t16 >> 4) & 7)) * 8;
      GLOAD_LDS(srcA + so, bts + t16 * 8);
    }
    GLOAD_LDS(mh + msplit * 2048 + tid * 4, mhl + tid * 4);
  }
  asm volatile("s_waitcnt vmcnt(0)" ::: "memory");
  __builtin_amdgcn_s_barrier();

  // A fragments -> registers (64 VGPRs), swizzled read.
  bf16x8 af[4][4];  // [mi][ks]
#pragma unroll
  for (int mi = 0; mi < 4; ++mi)
#pragma unroll
    for (int ks = 0; ks < 4; ++ks) {
      const int row = wm * 64 + mi * 16 + l15;
      const int cb = (ks * 64 + l4 * 16) ^ sw;
      af[mi][ks] = *(const bf16x8*)&bts[row * CDIM + (cb >> 1)];
    }
  __syncthreads();  // all waves done reading A; buffers free

  // Stage tiles 0 and 1 into buffers 0 and 1.
  const u16* mbase_ptr = mb + (size_t)(msplit * 2048) * CDIM;
#pragma unroll
  for (int tt = 0; tt < 2; ++tt)
#pragma unroll
    for (int c = 0; c < 4; ++c) {
      const int t16 = c * 512 + tid;
      const int so = (t16 ^ ((t16 >> 4) & 7)) * 8;
      GLOAD_LDS(mbase_ptr + (size_t)tt * BTROWS * CDIM + so,
                bts + tt * BTROWS * CDIM + t16 * 8);
    }
  // Own tile-0 chunks retired before the barrier -> union over waves = all.
  asm volatile("s_waitcnt vmcnt(4)" ::: "memory");
  __builtin_amdgcn_s_barrier();

  float tmax[4][4];
#pragma unroll
  for (int mi = 0; mi < 4; ++mi)
#pragma unroll
    for (int j = 0; j < 4; ++j) tmax[mi][j] = -3.0e38f;

  f32x4 acc[4][4];  // [mi][p]
  int cur = 0;      // t % 3

  for (int t = 0; t < NTILE; ++t) {
    const u16* bt = bts + cur * BTROWS * CDIM;
    int stg = cur + 2; if (stg >= 3) stg -= 3;
    u16* stgbuf = bts + stg * BTROWS * CDIM;
    const u16* srcT2 = mbase_ptr + (size_t)((t + 2) & (NTILE - 1)) * BTROWS * CDIM;

#pragma unroll
    for (int p = 0; p < 4; ++p) {
      // Fold previous tile's column-group p, then reseed with -m2/2.
      if (t) {
#pragma unroll
        for (int mi = 0; mi < 4; ++mi)
#pragma unroll
          for (int j = 0; j < 4; ++j)
            tmax[mi][j] = fmaxf(tmax[mi][j], acc[mi][p][j]);
      }
      const float mhv = mhl[t * BTROWS + wn * 64 + p * 16 + l15];
#pragma unroll
      for (int mi = 0; mi < 4; ++mi)
        acc[mi][p] = (f32x4){mhv, mhv, mhv, mhv};

      // This phase's B fragments (tile t, column-group p).
      bf16x8 bg[4];
      {
        const int row = wn * 64 + p * 16 + l15;
#pragma unroll
        for (int ks = 0; ks < 4; ++ks) {
          const int cb = (ks * 64 + l4 * 16) ^ sw;
          bg[ks] = *(const bf16x8*)&bt[row * CDIM + (cb >> 1)];
        }
      }
      // Stage chunk p of tile t+2 (lands ~2 tiles from now).
      {
        const int t16 = p * 512 + tid;
        const int so = (t16 ^ ((t16 >> 4) & 7)) * 8;
        GLOAD_LDS(srcT2 + so, stgbuf + t16 * 8);
      }
      if (p == 3)  // waits tile t+1's chunks (issued a full tile ago);
                   // tile t+2's 4 remain in flight across the barrier.
        asm volatile("s_waitcnt vmcnt(4)" ::: "memory");
      __builtin_amdgcn_s_barrier();
      __builtin_amdgcn_sched_barrier(0);
      __builtin_amdgcn_s_setprio(1);
#pragma unroll
      for (int ks = 0; ks < 4; ++ks)
#pragma unroll
        for (int mi = 0; mi < 4; ++mi)
          acc[mi][p] = __builtin_amdgcn_mfma_f32_16x16x32_bf16(
              af[mi][ks], bg[ks], acc[mi][p], 0, 0, 0);
      __builtin_amdgcn_s_setprio(0);
      __builtin_amdgcn_sched_barrier(0);
    }
    cur += 1; if (cur >= 3) cur -= 3;
  }

  // Fold the last tile's accumulators.
#pragma unroll
  for (int p = 0; p < 4; ++p)
#pragma unroll
    for (int mi = 0; mi < 4; ++mi)
#pragma unroll
      for (int j = 0; j < 4; ++j)
        tmax[mi][j] = fmaxf(tmax[mi][j], acc[mi][p][j]);

  // Max across the 16 lanes (l15) holding a row's columns.
#pragma unroll
  for (int mi = 0; mi < 4; ++mi)
#pragma unroll
    for (int j = 0; j < 4; ++j) {
      float tv = tmax[mi][j];
      tv = fmaxf(tv, __shfl_xor(tv, 1, 64));
      tv = fmaxf(tv, __shfl_xor(tv, 2, 64));
      tv = fmaxf(tv, __shfl_xor(tv, 4, 64));
      tv = fmaxf(tv, __shfl_xor(tv, 8, 64));
      tmax[mi][j] = tv;
    }
  if (l15 == 0) {
#pragma unroll
    for (int mi = 0; mi < 4; ++mi)
#pragma unroll
      for (int j = 0; j < 4; ++j) {
        const int row = nbase + wm * 64 + mi * 16 + l4 * 4 + j;
        // d2 = f2 + min(m2 - 2*cross) = f2 - 2*max(acc); >= 0 -> int-ordered
        const float d2 = fmaxf(fmaf(-2.0f, tmax[mi][j], f2[row]), 0.0f);
        atomicMin(&mind2[row], __float_as_int(d2));
      }
  }
}

__global__ __launch_bounds__(256) void finalize_kernel(
    const int* __restrict__ mind2, float* __restrict__ out)
{
  const int i = blockIdx.x * 256 + threadIdx.x;
  out[i] = sqrtf(fmaxf(__int_as_float(mind2[i]), 0.0f));
}

extern "C" void kernel_launch(void* const* d_in, const int* in_sizes, int n_in,
                              void* d_out, int out_size, void* d_ws, size_t ws_size,
                              hipStream_t stream) {
  const float* f = (const float*)d_in[0];  // features  [8192,1,1,128] fp32
  const float* m = (const float*)d_in[1];  // patch_mem [1,16384,1,128] fp32

  char* ws = (char*)d_ws;
  u16*  fb    = (u16*)(ws);                                   // 2 MB
  u16*  mb    = (u16*)(ws + (2u << 20));                      // 4 MB
  float* f2   = (float*)(ws + (2u << 20) + (4u << 20));       // 32 KB
  float* mh   = (float*)(ws + (2u << 20) + (4u << 20) + (32u << 10));  // 64 KB
  int*  mind2 = (int*)(ws + (2u << 20) + (4u << 20) + (96u << 10));    // 32 KB

  hipLaunchKernelGGL(prep_kernel, dim3((N_ROWS + M_ROWS) / 4), dim3(256), 0, stream,
                     f, m, fb, mb, f2, mh, mind2);
  hipLaunchKernelGGL(gemm_min_kernel, dim3(8, N_ROWS / 256), dim3(512), 0, stream,
                     fb, mb, f2, mh, mind2);
  hipLaunchKernelGGL(finalize_kernel, dim3(N_ROWS / 256), dim3(256), 0, stream,
                     mind2, (float*)d_out);
}